// Round 8
// baseline (365.619 us; speedup 1.0000x reference)
//
#include <hip/hip_runtime.h>
#include <hip/hip_bf16.h>
#include <stdint.h>

// ---------------------------------------------------------------------------
// TernaryExpert: out = TL(gelu(TL(x, w_up)), w_down)
//   TL(x,w) = rmsnorm(x) @ ternary(w)^T
// M = 16384, d_model = 1024, d_ff = 4096. Output f32 [16384,1024].
// GEMM (occupancy variant): 256x128 tile, BK=32, 512 thr (8 waves 4Mx2N,
// 64x64/wave), 16x16x32 MFMA, TRIPLE-buffered 72KB LDS -> 2 blocks/CU
// (launch_bounds(512,4), VGPR<=128). Stage t+2 each iter; vmcnt(3) waits only
// for loads issued a full iter ago (steady-state ~0 stall). One barrier/iter.
// BK=32 line-paired XOR swizzle (2 rows per 128B line), 2-way = free.
// ---------------------------------------------------------------------------

#define M_ROWS   16384
#define D_MODEL  1024
#define D_FF     4096
#define NW       (D_FF * D_MODEL)

typedef __attribute__((ext_vector_type(8))) short bf16x8;
typedef __attribute__((ext_vector_type(4))) float f32x4;
typedef __attribute__((ext_vector_type(8))) unsigned short u16x8;

__device__ __forceinline__ unsigned short f2bf(float f) {
    unsigned u = __builtin_bit_cast(unsigned, f);
    u += 0x7FFFu + ((u >> 16) & 1u);          // RNE
    return (unsigned short)(u >> 16);
}
__device__ __forceinline__ float bf2f(unsigned short h) {
    return __builtin_bit_cast(float, ((unsigned)h) << 16);
}

__device__ __forceinline__ void gload_lds16(const void* g, void* l) {
    __builtin_amdgcn_global_load_lds(
        (const __attribute__((address_space(1))) void*)g,
        (__attribute__((address_space(3))) void*)l, 16, 0, 0);
}

__device__ __forceinline__ void barrier_raw() {
    asm volatile("" ::: "memory");
    __builtin_amdgcn_sched_barrier(0);
    __builtin_amdgcn_s_barrier();
    __builtin_amdgcn_sched_barrier(0);
    asm volatile("" ::: "memory");
}

#define LGKM0()  do { asm volatile("s_waitcnt lgkmcnt(0)" ::: "memory"); \
                      __builtin_amdgcn_sched_barrier(0); } while (0)
#define VMCNT3() do { asm volatile("s_waitcnt vmcnt(3)" ::: "memory"); \
                      __builtin_amdgcn_sched_barrier(0); } while (0)
#define VMCNT0() do { asm volatile("s_waitcnt vmcnt(0)" ::: "memory"); \
                      __builtin_amdgcn_sched_barrier(0); } while (0)

__device__ __forceinline__ float gelu_fast(float v) {
    float w = v * v;
    float z = v * __builtin_fmaf(w, 0.07135481627f, 1.5957691216f);
    float e = __expf(-z);
    return v / (1.0f + e);
}

// ---------------------------------------------------------------------------
// aux kernels
// ---------------------------------------------------------------------------
__global__ __launch_bounds__(256) void absmean_reduce(const float* __restrict__ w,
                                                      double* __restrict__ asum) {
    const int n4 = NW / 4;
    float s = 0.f;
    const float4* w4 = (const float4*)w;
    for (int i = blockIdx.x * blockDim.x + threadIdx.x; i < n4;
         i += gridDim.x * blockDim.x) {
        float4 v = w4[i];
        s += fabsf(v.x) + fabsf(v.y) + fabsf(v.z) + fabsf(v.w);
    }
    #pragma unroll
    for (int off = 32; off > 0; off >>= 1) s += __shfl_down(s, off);
    __shared__ float sm[4];
    int lane = threadIdx.x & 63, wid = threadIdx.x >> 6;
    if (lane == 0) sm[wid] = s;
    __syncthreads();
    if (threadIdx.x == 0) {
        float t = sm[0] + sm[1] + sm[2] + sm[3];
        atomicAdd(asum, (double)t);
    }
}

__global__ __launch_bounds__(256) void quant_kernel(const float* __restrict__ w,
                                                    const double* __restrict__ asum,
                                                    unsigned short* __restrict__ wq) {
    float thr = (float)(0.5 * (*asum) * (1.0 / (double)NW));
    int i = blockIdx.x * blockDim.x + threadIdx.x;
    float4 v = ((const float4*)w)[i];
    ushort4 o;
    o.x = (fabsf(v.x) > thr) ? (v.x > 0.f ? 0x3F80 : 0xBF80) : 0;
    o.y = (fabsf(v.y) > thr) ? (v.y > 0.f ? 0x3F80 : 0xBF80) : 0;
    o.z = (fabsf(v.z) > thr) ? (v.z > 0.f ? 0x3F80 : 0xBF80) : 0;
    o.w = (fabsf(v.w) > thr) ? (v.w > 0.f ? 0x3F80 : 0xBF80) : 0;
    ((ushort4*)wq)[i] = o;
}

__global__ __launch_bounds__(256) void rmsnorm_x(const float* __restrict__ x,
                                                 unsigned short* __restrict__ xn) {
    const int row = blockIdx.x;
    const float4* xr = (const float4*)(x + (size_t)row * D_MODEL);
    float4 v = xr[threadIdx.x];
    float ss = v.x * v.x + v.y * v.y + v.z * v.z + v.w * v.w;
    #pragma unroll
    for (int off = 32; off > 0; off >>= 1) ss += __shfl_down(ss, off);
    __shared__ float sm[4];
    int lane = threadIdx.x & 63, wid = threadIdx.x >> 6;
    if (lane == 0) sm[wid] = ss;
    __syncthreads();
    float tot = sm[0] + sm[1] + sm[2] + sm[3];
    float s = 1.0f / (sqrtf(tot) * (1.0f / 32.0f) + 1e-8f);
    ushort4 o;
    o.x = f2bf(v.x * s); o.y = f2bf(v.y * s);
    o.z = f2bf(v.z * s); o.w = f2bf(v.w * s);
    ((ushort4*)(xn + (size_t)row * D_MODEL))[threadIdx.x] = o;
}

__global__ __launch_bounds__(256) void rowscale_h(const unsigned short* __restrict__ h,
                                                  float* __restrict__ rs) {
    const int row = blockIdx.x;
    const u16x8* hr = (const u16x8*)(h + (size_t)row * D_FF);
    u16x8 a = hr[threadIdx.x * 2 + 0];
    u16x8 b = hr[threadIdx.x * 2 + 1];
    float ss = 0.f;
    #pragma unroll
    for (int j = 0; j < 8; ++j) { float f = bf2f(a[j]); ss += f * f; }
    #pragma unroll
    for (int j = 0; j < 8; ++j) { float f = bf2f(b[j]); ss += f * f; }
    #pragma unroll
    for (int off = 32; off > 0; off >>= 1) ss += __shfl_down(ss, off);
    __shared__ float sm[4];
    int lane = threadIdx.x & 63, wid = threadIdx.x >> 6;
    if (lane == 0) sm[wid] = ss;
    __syncthreads();
    if (threadIdx.x == 0) {
        float tot = sm[0] + sm[1] + sm[2] + sm[3];
        rs[row] = 1.0f / (sqrtf(tot) * (1.0f / 64.0f) + 1e-8f);
    }
}

// ---------------------------------------------------------------------------
// GEMM: C[m][n] = sum_k A[m,k]*B[n,k]   (both K-contiguous)
// LDS buffer layout (24KB): A tile 256x32 bf16 @0 (16KB), B tile 128x32 @16384
// (8KB). Line-paired swizzle: element (row,kchunk c) at byte
//   (row>>1)*128 + (((row&1)*4+c) ^ ((row>>1)&7))*16       (c = k/8, 0..3)
// gload dst is linear tid*16; source is pre-inverse-swizzled:
//   slot tid -> line=tid>>3, chunk=tid&7, q=chunk^(line&7),
//   row=2*line+(q>>2), c=q&3.
// ---------------------------------------------------------------------------
template <int EPI, int KDIM, int NBLKN>
__global__ __launch_bounds__(512, 4) void gemm_occ(const unsigned short* __restrict__ A,
                                                   const unsigned short* __restrict__ B,
                                                   unsigned short* __restrict__ Cbf,
                                                   float* __restrict__ Cf,
                                                   const float* __restrict__ rowscale,
                                                   int nwg) {
    constexpr int BUFB = 24576;
    constexpr int NT = KDIM / 32;
    __shared__ char smem[3 * BUFB];

    const int tid = threadIdx.x;
    const int bid = blockIdx.x;
    const int swz = (bid & 7) * (nwg >> 3) + (bid >> 3);
    const uint m0 = (uint)(swz / NBLKN) * 256u;
    const uint n0 = (uint)(swz % NBLKN) * 128u;

    const int lane = tid & 63;
    const int wid  = tid >> 6;
    const int wm   = wid >> 1;                  // 0..3 -> 64-row slice
    const int wn   = wid & 1;                   // 0..1 -> 64-col slice
    const int lr   = lane & 15;
    const int lk   = lane >> 4;

    // staging source mapping (inverse of the line-paired swizzle)
    const uint q    = (uint)((tid & 7) ^ ((tid >> 3) & 7));
    const uint rowL = (uint)(((tid >> 3) << 1) | (q >> 2));
    const uint colL = (q & 3) * 8u;
    const uint aOff0 = (m0 + rowL) * (uint)KDIM + colL;
    const uint aOff1 = (m0 + 128u + rowL) * (uint)KDIM + colL;
    const uint bOff  = (n0 + rowL) * (uint)KDIM + colL;
    const uint dstOff = (uint)tid * 16u;

    // fragment read offsets (bytes)
    uint offA[4], offB[4];
    #pragma unroll
    for (int i = 0; i < 4; ++i) {
        uint row = (uint)(wm * 64 + i * 16 + lr);
        offA[i] = (row >> 1) * 128u +
                  (((((row & 1u) << 2) | (uint)lk) ^ ((row >> 1) & 7u)) << 4);
        uint rowb = (uint)(wn * 64 + i * 16 + lr);
        offB[i] = 16384u + (rowb >> 1) * 128u +
                  (((((rowb & 1u) << 2) | (uint)lk) ^ ((rowb >> 1) & 7u)) << 4);
    }

    f32x4 acc[4][4];
    #pragma unroll
    for (int mi = 0; mi < 4; ++mi)
        #pragma unroll
        for (int ni = 0; ni < 4; ++ni)
            acc[mi][ni] = (f32x4){0.f, 0.f, 0.f, 0.f};

    // prologue: stage tiles 0 and 1
    #pragma unroll
    for (int tt = 0; tt < 2; ++tt) {
        char* sb = smem + tt * BUFB;
        const uint k0 = (uint)tt * 32u;
        gload_lds16(A + aOff0 + k0, sb + dstOff);
        gload_lds16(A + aOff1 + k0, sb + 8192 + dstOff);
        gload_lds16(B + bOff  + k0, sb + 16384 + dstOff);
    }
    VMCNT3();            // tile 0 landed; tile 1 in flight
    barrier_raw();

    int cur = 0, s2 = 2;
    #pragma unroll 1
    for (int t = 0; t < NT; ++t) {
        const char* cb = smem + cur * BUFB;
        const bool doStage = (t + 2 < NT);
        if (doStage) {
            char* sb = smem + s2 * BUFB;
            const uint k0 = (uint)(t + 2) * 32u;
            gload_lds16(A + aOff0 + k0, sb + dstOff);
            gload_lds16(A + aOff1 + k0, sb + 8192 + dstOff);
            gload_lds16(B + bOff  + k0, sb + 16384 + dstOff);
        }
        bf16x8 av[4], bv[4];
        #pragma unroll
        for (int i = 0; i < 4; ++i) av[i] = *(const bf16x8*)(cb + offA[i]);
        #pragma unroll
        for (int i = 0; i < 4; ++i) bv[i] = *(const bf16x8*)(cb + offB[i]);
        LGKM0();
        __builtin_amdgcn_s_setprio(1);
        #pragma unroll
        for (int mi = 0; mi < 4; ++mi)
            #pragma unroll
            for (int ni = 0; ni < 4; ++ni)
                acc[mi][ni] = __builtin_amdgcn_mfma_f32_16x16x32_bf16(
                    av[mi], bv[ni], acc[mi][ni], 0, 0, 0);
        __builtin_amdgcn_s_setprio(0);
        if (doStage) VMCNT3(); else VMCNT0();   // t+1 landed; t+2 in flight
        barrier_raw();
        cur = (cur == 2) ? 0 : cur + 1;
        s2  = (s2  == 2) ? 0 : s2  + 1;
    }

    // epilogue: C/D frag mapping col = lane&15, row = (lane>>4)*4 + reg
    constexpr uint N = (uint)NBLKN * 128u;
    #pragma unroll
    for (int mi = 0; mi < 4; ++mi) {
        #pragma unroll
        for (int j = 0; j < 4; ++j) {
            const uint gr = m0 + (uint)(wm * 64 + mi * 16 + lk * 4 + j);
            float s = 0.f;
            if (EPI == 1) s = rowscale[gr];
            #pragma unroll
            for (int ni = 0; ni < 4; ++ni) {
                const uint gc = n0 + (uint)(wn * 64 + ni * 16 + lr);
                float v = acc[mi][ni][j];
                if (EPI == 0) {
                    Cbf[gr * N + gc] = f2bf(gelu_fast(v));
                } else {
                    Cf[gr * N + gc] = v * s;
                }
            }
        }
    }
}

// ---------------------------------------------------------------------------
extern "C" void kernel_launch(void* const* d_in, const int* in_sizes, int n_in,
                              void* d_out, int out_size, void* d_ws, size_t ws_size,
                              hipStream_t stream) {
    const float* x    = (const float*)d_in[0];
    const float* w_up = (const float*)d_in[1];
    const float* w_dn = (const float*)d_in[2];
    float* out = (float*)d_out;

    uint8_t* ws = (uint8_t*)d_ws;
    unsigned short* h   = (unsigned short*)(ws);                       // 128 MB
    unsigned short* xn  = (unsigned short*)(ws + 134217728);           // 32 MB
    unsigned short* wqu = (unsigned short*)(ws + 134217728 + 33554432);
    unsigned short* wqd = (unsigned short*)(ws + 134217728 + 33554432 + 8388608);
    float*  rs   = (float*)(ws + 134217728 + 33554432 + 2 * 8388608);
    double* alph = (double*)(ws + 134217728 + 33554432 + 2 * 8388608 + 65536);

    hipMemsetAsync(alph, 0, 16, stream);

    absmean_reduce<<<256, 256, 0, stream>>>(w_up, alph + 0);
    absmean_reduce<<<256, 256, 0, stream>>>(w_dn, alph + 1);
    quant_kernel<<<NW / 1024, 256, 0, stream>>>(w_up, alph + 0, wqu);
    quant_kernel<<<NW / 1024, 256, 0, stream>>>(w_dn, alph + 1, wqd);
    rmsnorm_x<<<M_ROWS, 256, 0, stream>>>(x, xn);

    // L1: h = gelu(xn @ wqu^T)  [16384 x 4096] -> 64x32 = 2048 blocks
    gemm_occ<0, D_MODEL, 32><<<2048, 512, 0, stream>>>(
        xn, wqu, h, nullptr, nullptr, 2048);

    rowscale_h<<<M_ROWS, 256, 0, stream>>>(h, rs);

    // L2: out = (h @ wqd^T) * rs[m]  [16384 x 1024] -> 64x8 = 512 blocks
    gemm_occ<1, D_FF, 8><<<512, 512, 0, stream>>>(
        h, wqd, nullptr, out, rs, 512);
}

// Round 9
// 334.629 us; speedup vs baseline: 1.0926x; 1.0926x over previous
//
#include <hip/hip_runtime.h>
#include <hip/hip_bf16.h>
#include <stdint.h>

// ---------------------------------------------------------------------------
// TernaryExpert: out = TL(gelu(TL(x, w_up)), w_down)
//   TL(x,w) = rmsnorm(x) @ ternary(w)^T
// M = 16384, d_model = 1024, d_ff = 4096. Output f32 [16384,1024].
// GEMM (B-in-regs variant): 256x256 tile, BK=64, 8 waves (2Mx4N, 128x64/wave),
// 16x16x32 MFMA. A: LDS triple-buffered (3x32KB), XOR-swizzled, gload_lds.
// B: ternary weights PRE-PACKED in MFMA-fragment order by the quant kernel;
// each wave loads its fragments directly global->VGPR (coalesced dwordx4,
// L2-hot), ping-pong reg sets via 2-tile-unrolled loop. 1 barrier / K-tile.
// Counted vmcnt discipline (outstanding sets traced; B loads inline-asm to
// pin issue order): end-of-tile vmcnt(10) publishes A0,A2(t+2)-staged-oldest;
// P1 vmcnt(4) lands B0-3(t); vmcnt(0) mid-P1 retires only >=1-tile-old loads.
// ---------------------------------------------------------------------------

#define M_ROWS   16384
#define D_MODEL  1024
#define D_FF     4096
#define NW       (D_FF * D_MODEL)

typedef __attribute__((ext_vector_type(8))) short bf16x8;
typedef __attribute__((ext_vector_type(4))) float f32x4;
typedef __attribute__((ext_vector_type(8))) unsigned short u16x8;

__device__ __forceinline__ unsigned short f2bf(float f) {
    unsigned u = __builtin_bit_cast(unsigned, f);
    u += 0x7FFFu + ((u >> 16) & 1u);          // RNE
    return (unsigned short)(u >> 16);
}
__device__ __forceinline__ float bf2f(unsigned short h) {
    return __builtin_bit_cast(float, ((unsigned)h) << 16);
}

__device__ __forceinline__ void gload_lds16(const void* g, void* l) {
    __builtin_amdgcn_global_load_lds(
        (const __attribute__((address_space(1))) void*)g,
        (__attribute__((address_space(3))) void*)l, 16, 0, 0);
}

__device__ __forceinline__ void barrier_raw() {
    asm volatile("" ::: "memory");
    __builtin_amdgcn_sched_barrier(0);
    __builtin_amdgcn_s_barrier();
    __builtin_amdgcn_sched_barrier(0);
    asm volatile("" ::: "memory");
}

#define LGKM0()   do { asm volatile("s_waitcnt lgkmcnt(0)" ::: "memory"); \
                       __builtin_amdgcn_sched_barrier(0); } while (0)
#define VMCNT(n)  do { asm volatile("s_waitcnt vmcnt(" #n ")" ::: "memory"); \
                       __builtin_amdgcn_sched_barrier(0); } while (0)

// B fragment load: 64 lanes x 16B contiguous (perfectly coalesced), to regs.
#define LOADB(dst, ptr) \
    asm volatile("global_load_dwordx4 %0, %1, off" : "=v"(dst) : "v"(ptr))

__device__ __forceinline__ float gelu_fast(float v) {
    float w = v * v;
    float z = v * __builtin_fmaf(w, 0.07135481627f, 1.5957691216f);
    float e = __expf(-z);
    return v / (1.0f + e);
}

// ---------------------------------------------------------------------------
// aux kernels
// ---------------------------------------------------------------------------
__global__ __launch_bounds__(256) void absmean_reduce(const float* __restrict__ w,
                                                      double* __restrict__ asum) {
    const int n4 = NW / 4;
    float s = 0.f;
    const float4* w4 = (const float4*)w;
    for (int i = blockIdx.x * blockDim.x + threadIdx.x; i < n4;
         i += gridDim.x * blockDim.x) {
        float4 v = w4[i];
        s += fabsf(v.x) + fabsf(v.y) + fabsf(v.z) + fabsf(v.w);
    }
    #pragma unroll
    for (int off = 32; off > 0; off >>= 1) s += __shfl_down(s, off);
    __shared__ float sm[4];
    int lane = threadIdx.x & 63, wid = threadIdx.x >> 6;
    if (lane == 0) sm[wid] = s;
    __syncthreads();
    if (threadIdx.x == 0) {
        float t = sm[0] + sm[1] + sm[2] + sm[3];
        atomicAdd(asum, (double)t);
    }
}

// Ternarize AND pack into MFMA-fragment order:
// frag (nf = row/16, ks = k/32), lane l = (k/8 % 4)*16 + row%16 holds
// rows nf*16+(l&15), k = ks*32 + (l>>4)*8 .. +8.  16B-slot index:
//   (nf*(K/32) + ks)*64 + lane
template <int K>
__global__ __launch_bounds__(256) void quant_pack(const float* __restrict__ w,
                                                  const double* __restrict__ asum,
                                                  unsigned short* __restrict__ wq) {
    constexpr int K8 = K / 8;
    float thr = (float)(0.5 * (*asum) * (1.0 / (double)NW));
    int g = blockIdx.x * blockDim.x + threadIdx.x;      // one 8-elem group
    int row = g / K8;
    int k8  = g - row * K8;
    int nf = row >> 4, lr = row & 15, ks = k8 >> 2, lk = k8 & 3;
    int lane = lk * 16 + lr;
    size_t dst = (size_t)(nf * (K / 32) + ks) * 64 + (size_t)lane;
    float4 v0 = ((const float4*)w)[g * 2];
    float4 v1 = ((const float4*)w)[g * 2 + 1];
    u16x8 o;
    o[0] = (fabsf(v0.x) > thr) ? (v0.x > 0.f ? 0x3F80 : 0xBF80) : 0;
    o[1] = (fabsf(v0.y) > thr) ? (v0.y > 0.f ? 0x3F80 : 0xBF80) : 0;
    o[2] = (fabsf(v0.z) > thr) ? (v0.z > 0.f ? 0x3F80 : 0xBF80) : 0;
    o[3] = (fabsf(v0.w) > thr) ? (v0.w > 0.f ? 0x3F80 : 0xBF80) : 0;
    o[4] = (fabsf(v1.x) > thr) ? (v1.x > 0.f ? 0x3F80 : 0xBF80) : 0;
    o[5] = (fabsf(v1.y) > thr) ? (v1.y > 0.f ? 0x3F80 : 0xBF80) : 0;
    o[6] = (fabsf(v1.z) > thr) ? (v1.z > 0.f ? 0x3F80 : 0xBF80) : 0;
    o[7] = (fabsf(v1.w) > thr) ? (v1.w > 0.f ? 0x3F80 : 0xBF80) : 0;
    ((u16x8*)wq)[dst] = o;
}

__global__ __launch_bounds__(256) void rmsnorm_x(const float* __restrict__ x,
                                                 unsigned short* __restrict__ xn) {
    const int row = blockIdx.x;
    const float4* xr = (const float4*)(x + (size_t)row * D_MODEL);
    float4 v = xr[threadIdx.x];
    float ss = v.x * v.x + v.y * v.y + v.z * v.z + v.w * v.w;
    #pragma unroll
    for (int off = 32; off > 0; off >>= 1) ss += __shfl_down(ss, off);
    __shared__ float sm[4];
    int lane = threadIdx.x & 63, wid = threadIdx.x >> 6;
    if (lane == 0) sm[wid] = ss;
    __syncthreads();
    float tot = sm[0] + sm[1] + sm[2] + sm[3];
    float s = 1.0f / (sqrtf(tot) * (1.0f / 32.0f) + 1e-8f);
    ushort4 o;
    o.x = f2bf(v.x * s); o.y = f2bf(v.y * s);
    o.z = f2bf(v.z * s); o.w = f2bf(v.w * s);
    ((ushort4*)(xn + (size_t)row * D_MODEL))[threadIdx.x] = o;
}

__global__ __launch_bounds__(256) void rowscale_h(const unsigned short* __restrict__ h,
                                                  float* __restrict__ rs) {
    const int row = blockIdx.x;
    const u16x8* hr = (const u16x8*)(h + (size_t)row * D_FF);
    u16x8 a = hr[threadIdx.x * 2 + 0];
    u16x8 b = hr[threadIdx.x * 2 + 1];
    float ss = 0.f;
    #pragma unroll
    for (int j = 0; j < 8; ++j) { float f = bf2f(a[j]); ss += f * f; }
    #pragma unroll
    for (int j = 0; j < 8; ++j) { float f = bf2f(b[j]); ss += f * f; }
    #pragma unroll
    for (int off = 32; off > 0; off >>= 1) ss += __shfl_down(ss, off);
    __shared__ float sm[4];
    int lane = threadIdx.x & 63, wid = threadIdx.x >> 6;
    if (lane == 0) sm[wid] = ss;
    __syncthreads();
    if (threadIdx.x == 0) {
        float tot = sm[0] + sm[1] + sm[2] + sm[3];
        rs[row] = 1.0f / (sqrtf(tot) * (1.0f / 64.0f) + 1e-8f);
    }
}

// ---------------------------------------------------------------------------
// GEMM: C[m][n] = sum_k A[m,k]*B[n,k]; A row-major K-contig, B pre-packed.
// ---------------------------------------------------------------------------
template <int EPI, int KDIM, int NBLKN>
__global__ __launch_bounds__(512, 2) void gemm_bg(const unsigned short* __restrict__ A,
                                                  const char* __restrict__ Bq,
                                                  unsigned short* __restrict__ Cbf,
                                                  float* __restrict__ Cf,
                                                  const float* __restrict__ rowscale,
                                                  int nwg) {
    constexpr int BUFB = 32768;
    constexpr int NT = KDIM / 64;
    constexpr int KS = KDIM / 32;
    __shared__ char smem[3 * BUFB];

    const int tid = threadIdx.x;
    const int bid = blockIdx.x;
    const int swz = (bid & 7) * (nwg >> 3) + (bid >> 3);
    const uint m0 = (uint)(swz / NBLKN) * 256u;
    const uint n0 = (uint)(swz % NBLKN) * 256u;

    const int lane = tid & 63;
    const int wid  = tid >> 6;
    const int wm   = wid >> 2;                  // 0..1 -> 128-row slice
    const int wn   = wid & 3;                   // 0..3 -> 64-col slice
    const int lr   = lane & 15;
    const int lk   = lane >> 4;

    // A staging: thread covers row (tid>>3) of a 64-row quarter, chunk tid&7,
    // pre-swizzled source (proven 0-conflict layout from R4/R7)
    const uint rowBase = (uint)(tid >> 3);
    const uint colE = (((uint)(tid & 7) << 4) ^ ((rowBase & 7u) << 4)) >> 1;
    const uint aBase = (m0 + rowBase) * (uint)KDIM + colE;
    const uint dstOff = (uint)tid * 16u;

    // A fragment read offsets
    const uint xorv = ((uint)(lr & 7)) << 4;
    const uint kb0 = (((uint)lk << 4)      ) ^ xorv;
    const uint kb1 = (((uint)lk << 4) | 64u) ^ xorv;
    uint offA[8];
    #pragma unroll
    for (int i = 0; i < 8; ++i)
        offA[i] = (uint)(wm * 128 + i * 16 + lr) * 128u;

    // B fragment base pointers (per wave): frag (nfBase+i, ks) at
    // byte ((nf*KS + ks)*64 + lane)*16;  ks step = 1024 B, tile step = 2048 B.
    const int nfBase = (int)(n0 >> 4) + wn * 4;
    const char* bPtr[4];
    #pragma unroll
    for (int i = 0; i < 4; ++i)
        bPtr[i] = Bq + ((size_t)(nfBase + i) * KS * 64 + (size_t)lane) * 16;

    f32x4 acc[8][4];
    #pragma unroll
    for (int mi = 0; mi < 8; ++mi)
        #pragma unroll
        for (int ni = 0; ni < 4; ++ni)
            acc[mi][ni] = (f32x4){0.f, 0.f, 0.f, 0.f};

    f32x4 bS0[8], bS1[8];   // B reg sets (even tile uses bS0, odd bS1)

    // ---- prologue: stage A(0),A(1) (order q0,q2,q1,q3 each), load B(0) ----
    {
        char* sb = smem;
        gload_lds16(A + aBase +   0u * KDIM, sb +     0 + dstOff);
        gload_lds16(A + aBase + 128u * KDIM, sb + 16384 + dstOff);
        gload_lds16(A + aBase +  64u * KDIM, sb +  8192 + dstOff);
        gload_lds16(A + aBase + 192u * KDIM, sb + 24576 + dstOff);
        sb = smem + BUFB;
        gload_lds16(A + aBase +   0u * KDIM + 64u, sb +     0 + dstOff);
        gload_lds16(A + aBase + 128u * KDIM + 64u, sb + 16384 + dstOff);
        gload_lds16(A + aBase +  64u * KDIM + 64u, sb +  8192 + dstOff);
        gload_lds16(A + aBase + 192u * KDIM + 64u, sb + 24576 + dstOff);
        #pragma unroll
        for (int i = 0; i < 4; ++i) LOADB(bS0[i],     bPtr[i]);
        #pragma unroll
        for (int i = 0; i < 4; ++i) LOADB(bS0[4 + i], bPtr[i] + 1024);
        __builtin_amdgcn_sched_barrier(0);
    }
    VMCNT(12);           // A(0) x4 landed
    barrier_raw();

    // ---- main loop: 2 tiles per iteration (static B reg ping-pong) ----
    int cur = 0;
    #pragma unroll 1
    for (int t = 0; t < NT; t += 2) {
        int c1 = cur + 1; if (c1 > 2) c1 -= 3;
        int c2 = c1 + 1;  if (c2 > 2) c2 -= 3;

#define TILE(T, CBUF, SBUF, BUSE, BLOAD)                                        \
        {                                                                       \
            const char* cb = smem + (CBUF) * BUFB;                              \
            char* sb = smem + (SBUF) * BUFB;                                    \
            const uint tc = (uint)((T) + 2) * 64u;                              \
            const bool doStage = ((T) + 2 < NT);                                \
            const bool doB = ((T) + 1 < NT);                                    \
            const size_t bko = (size_t)((T) + 1) * 2048;                        \
            bf16x8 av0[4], av1[4];                                              \
            /* P1: A-h0 */                                                      \
            _Pragma("unroll")                                                   \
            for (int i = 0; i < 4; ++i) {                                       \
                av0[i] = *(const bf16x8*)(cb + offA[i] + kb0);                   \
                av1[i] = *(const bf16x8*)(cb + offA[i] + kb1);                   \
            }                                                                   \
            LGKM0();                                                            \
            VMCNT(4);  /* B0-3(T) landed */                                     \
            __builtin_amdgcn_s_setprio(1);                                      \
            _Pragma("unroll")                                                   \
            for (int mi = 0; mi < 4; ++mi)                                      \
                _Pragma("unroll")                                               \
                for (int ni = 0; ni < 4; ++ni)                                  \
                    acc[mi][ni] = __builtin_amdgcn_mfma_f32_16x16x32_bf16(      \
                        av0[mi], __builtin_bit_cast(bf16x8, BUSE[ni]),          \
                        acc[mi][ni], 0, 0, 0);                                  \
            VMCNT(0);  /* B4-7(T) (issued >=0.7 tile ago) */                    \
            _Pragma("unroll")                                                   \
            for (int mi = 0; mi < 4; ++mi)                                      \
                _Pragma("unroll")                                               \
                for (int ni = 0; ni < 4; ++ni)                                  \
                    acc[mi][ni] = __builtin_amdgcn_mfma_f32_16x16x32_bf16(      \
                        av1[mi], __builtin_bit_cast(bf16x8, BUSE[4 + ni]),      \
                        acc[mi][ni], 0, 0, 0);                                  \
            __builtin_amdgcn_s_setprio(0);                                      \
            if (doStage) {  /* stage A(T+2): q0,q2,q1,q3 */                     \
                gload_lds16(A + aBase +   0u * KDIM + tc, sb +     0 + dstOff); \
                gload_lds16(A + aBase + 128u * KDIM + tc, sb + 16384 + dstOff); \
                gload_lds16(A + aBase +  64u * KDIM + tc, sb +  8192 + dstOff); \
                gload_lds16(A + aBase + 192u * KDIM + tc, sb + 24576 + dstOff); \
            }                                                                   \
            __builtin_amdgcn_sched_barrier(0);                                  \
            /* P2: A-h1 */                                                      \
            _Pragma("unroll")                                                   \
            for (int i = 0; i < 4; ++i) {                                       \
                av0[i] = *(const bf16x8*)(cb + offA[4 + i] + kb0);               \
                av1[i] = *(const bf16x8*)(cb + offA[4 + i] + kb1);               \
            }                                                                   \
            LGKM0();                                                            \
            __builtin_amdgcn_s_setprio(1);                                      \
            _Pragma("unroll")                                                   \
            for (int mi = 0; mi < 4; ++mi)                                      \
                _Pragma("unroll")                                               \
                for (int ni = 0; ni < 4; ++ni)                                  \
                    acc[4 + mi][ni] = __builtin_amdgcn_mfma_f32_16x16x32_bf16(  \
                        av0[mi], __builtin_bit_cast(bf16x8, BUSE[ni]),          \
                        acc[4 + mi][ni], 0, 0, 0);                              \
            _Pragma("unroll")                                                   \
            for (int mi = 0; mi < 4; ++mi)                                      \
                _Pragma("unroll")                                               \
                for (int ni = 0; ni < 4; ++ni)                                  \
                    acc[4 + mi][ni] = __builtin_amdgcn_mfma_f32_16x16x32_bf16(  \
                        av1[mi], __builtin_bit_cast(bf16x8, BUSE[4 + ni]),      \
                        acc[4 + mi][ni], 0, 0, 0);                              \
            __builtin_amdgcn_s_setprio(0);                                      \
            if (doB) {  /* load B(T+1): kk0 frags first, then kk1 */            \
                _Pragma("unroll")                                               \
                for (int i = 0; i < 4; ++i) LOADB(BLOAD[i],     bPtr[i] + bko); \
                _Pragma("unroll")                                               \
                for (int i = 0; i < 4; ++i) LOADB(BLOAD[4 + i],                 \
                                                  bPtr[i] + bko + 1024);        \
            }                                                                   \
            __builtin_amdgcn_sched_barrier(0);                                  \
            VMCNT(10);  /* A-q0,q2(T+2) landed (oldest of A4+B8) */             \
            barrier_raw();                                                      \
        }

        TILE(t,     cur, c2,  bS0, bS1)
        TILE(t + 1, c1,  cur, bS1, bS0)
#undef TILE
        cur = c2;
    }

    // epilogue: C/D frag mapping col = lane&15, row = (lane>>4)*4 + reg
    constexpr uint N = (uint)NBLKN * 256u;
    #pragma unroll
    for (int mi = 0; mi < 8; ++mi) {
        #pragma unroll
        for (int j = 0; j < 4; ++j) {
            const uint gr = m0 + (uint)(wm * 128 + mi * 16 + lk * 4 + j);
            float s = 0.f;
            if (EPI == 1) s = rowscale[gr];
            #pragma unroll
            for (int ni = 0; ni < 4; ++ni) {
                const uint gc = n0 + (uint)(wn * 64 + ni * 16 + lr);
                float v = acc[mi][ni][j];
                if (EPI == 0) {
                    Cbf[gr * N + gc] = f2bf(gelu_fast(v));
                } else {
                    Cf[gr * N + gc] = v * s;
                }
            }
        }
    }
}

// ---------------------------------------------------------------------------
extern "C" void kernel_launch(void* const* d_in, const int* in_sizes, int n_in,
                              void* d_out, int out_size, void* d_ws, size_t ws_size,
                              hipStream_t stream) {
    const float* x    = (const float*)d_in[0];
    const float* w_up = (const float*)d_in[1];
    const float* w_dn = (const float*)d_in[2];
    float* out = (float*)d_out;

    uint8_t* ws = (uint8_t*)d_ws;
    unsigned short* h   = (unsigned short*)(ws);                       // 128 MB
    unsigned short* xn  = (unsigned short*)(ws + 134217728);           // 32 MB
    unsigned short* wqu = (unsigned short*)(ws + 134217728 + 33554432);
    unsigned short* wqd = (unsigned short*)(ws + 134217728 + 33554432 + 8388608);
    float*  rs   = (float*)(ws + 134217728 + 33554432 + 2 * 8388608);
    double* alph = (double*)(ws + 134217728 + 33554432 + 2 * 8388608 + 65536);

    hipMemsetAsync(alph, 0, 16, stream);

    absmean_reduce<<<256, 256, 0, stream>>>(w_up, alph + 0);
    absmean_reduce<<<256, 256, 0, stream>>>(w_dn, alph + 1);
    quant_pack<D_MODEL><<<NW / 2048, 256, 0, stream>>>(w_up, alph + 0, wqu);
    quant_pack<D_FF><<<NW / 2048, 256, 0, stream>>>(w_dn, alph + 1, wqd);
    rmsnorm_x<<<M_ROWS, 256, 0, stream>>>(x, xn);

    // L1: h = gelu(xn @ wqu^T)  [16384 x 4096] -> 64x16 = 1024 blocks
    gemm_bg<0, D_MODEL, 16><<<1024, 512, 0, stream>>>(
        xn, (const char*)wqu, h, nullptr, nullptr, 1024);

    rowscale_h<<<M_ROWS, 256, 0, stream>>>(h, rs);

    // L2: out = (h @ wqd^T) * rs[m]  [16384 x 1024] -> 64x4 = 256 blocks
    gemm_bg<1, D_FF, 4><<<256, 512, 0, stream>>>(
        h, (const char*)wqd, nullptr, out, rs, 256);
}

// Round 10
// 331.850 us; speedup vs baseline: 1.1018x; 1.0084x over previous
//
#include <hip/hip_runtime.h>
#include <hip/hip_bf16.h>
#include <stdint.h>

// ---------------------------------------------------------------------------
// TernaryExpert: out = TL(gelu(TL(x, w_up)), w_down)
//   TL(x,w) = rmsnorm(x) @ ternary(w)^T
// M = 16384, d_model = 1024, d_ff = 4096. Output f32 [16384,1024].
// GEMM: faithful m201 8-phase port. 256x256, BK=64, 8 waves (2Mx4N,
// 128x64/wave), 16x16x32 MFMA. 2 K-tiles per iteration, 8 phases, DUAL
// barriers per phase, one 16KB half-tile staged per phase (WAR-safe by the
// barrier rhythm), vmcnt(6)@ph4 / vmcnt(8)@ph8 only (16-deep in flight,
// waits target loads issued a full iteration earlier). Reads per phase
// {12,4,8,0} with A/B fragment register reuse across quadrants.
// Ledger: iter j stages tiles 2j+2 (ph2,3,4,5) and 2j+3 (ph6,7,8,8).
//  ph4: outstanding = [2j+1:8]+[6] -> vmcnt(6) retires 2j+1 (used from ph5).
//  ph8: outstanding = [2j+2:8]+[2j+3:8] -> vmcnt(8) retires 2j+2 (next ph1).
// ---------------------------------------------------------------------------

#define M_ROWS   16384
#define D_MODEL  1024
#define D_FF     4096
#define NW       (D_FF * D_MODEL)

typedef __attribute__((ext_vector_type(8))) short bf16x8;
typedef __attribute__((ext_vector_type(4))) float f32x4;
typedef __attribute__((ext_vector_type(8))) unsigned short u16x8;

__device__ __forceinline__ unsigned short f2bf(float f) {
    unsigned u = __builtin_bit_cast(unsigned, f);
    u += 0x7FFFu + ((u >> 16) & 1u);          // RNE
    return (unsigned short)(u >> 16);
}
__device__ __forceinline__ float bf2f(unsigned short h) {
    return __builtin_bit_cast(float, ((unsigned)h) << 16);
}

__device__ __forceinline__ void gload_lds16(const void* g, void* l) {
    __builtin_amdgcn_global_load_lds(
        (const __attribute__((address_space(1))) void*)g,
        (__attribute__((address_space(3))) void*)l, 16, 0, 0);
}

__device__ __forceinline__ void barrier_raw() {
    asm volatile("" ::: "memory");
    __builtin_amdgcn_sched_barrier(0);
    __builtin_amdgcn_s_barrier();
    __builtin_amdgcn_sched_barrier(0);
    asm volatile("" ::: "memory");
}

#define LGKM0()   do { asm volatile("s_waitcnt lgkmcnt(0)" ::: "memory"); \
                       __builtin_amdgcn_sched_barrier(0); } while (0)
#define LGKM8()   do { asm volatile("s_waitcnt lgkmcnt(8)" ::: "memory"); \
                       __builtin_amdgcn_sched_barrier(0); } while (0)
#define VMCNT(n)  do { asm volatile("s_waitcnt vmcnt(" #n ")" ::: "memory"); \
                       __builtin_amdgcn_sched_barrier(0); } while (0)

__device__ __forceinline__ float gelu_fast(float v) {
    float w = v * v;
    float z = v * __builtin_fmaf(w, 0.07135481627f, 1.5957691216f);
    float e = __expf(-z);
    return v / (1.0f + e);
}

// ---------------------------------------------------------------------------
// aux kernels
// ---------------------------------------------------------------------------
__global__ __launch_bounds__(256) void absmean_reduce(const float* __restrict__ w,
                                                      double* __restrict__ asum) {
    const int n4 = NW / 4;
    float s = 0.f;
    const float4* w4 = (const float4*)w;
    for (int i = blockIdx.x * blockDim.x + threadIdx.x; i < n4;
         i += gridDim.x * blockDim.x) {
        float4 v = w4[i];
        s += fabsf(v.x) + fabsf(v.y) + fabsf(v.z) + fabsf(v.w);
    }
    #pragma unroll
    for (int off = 32; off > 0; off >>= 1) s += __shfl_down(s, off);
    __shared__ float sm[4];
    int lane = threadIdx.x & 63, wid = threadIdx.x >> 6;
    if (lane == 0) sm[wid] = s;
    __syncthreads();
    if (threadIdx.x == 0) {
        float t = sm[0] + sm[1] + sm[2] + sm[3];
        atomicAdd(asum, (double)t);
    }
}

__global__ __launch_bounds__(256) void quant_kernel(const float* __restrict__ w,
                                                    const double* __restrict__ asum,
                                                    unsigned short* __restrict__ wq) {
    float thr = (float)(0.5 * (*asum) * (1.0 / (double)NW));
    int i = blockIdx.x * blockDim.x + threadIdx.x;
    float4 v = ((const float4*)w)[i];
    ushort4 o;
    o.x = (fabsf(v.x) > thr) ? (v.x > 0.f ? 0x3F80 : 0xBF80) : 0;
    o.y = (fabsf(v.y) > thr) ? (v.y > 0.f ? 0x3F80 : 0xBF80) : 0;
    o.z = (fabsf(v.z) > thr) ? (v.z > 0.f ? 0x3F80 : 0xBF80) : 0;
    o.w = (fabsf(v.w) > thr) ? (v.w > 0.f ? 0x3F80 : 0xBF80) : 0;
    ((ushort4*)wq)[i] = o;
}

__global__ __launch_bounds__(256) void rmsnorm_x(const float* __restrict__ x,
                                                 unsigned short* __restrict__ xn) {
    const int row = blockIdx.x;
    const float4* xr = (const float4*)(x + (size_t)row * D_MODEL);
    float4 v = xr[threadIdx.x];
    float ss = v.x * v.x + v.y * v.y + v.z * v.z + v.w * v.w;
    #pragma unroll
    for (int off = 32; off > 0; off >>= 1) ss += __shfl_down(ss, off);
    __shared__ float sm[4];
    int lane = threadIdx.x & 63, wid = threadIdx.x >> 6;
    if (lane == 0) sm[wid] = ss;
    __syncthreads();
    float tot = sm[0] + sm[1] + sm[2] + sm[3];
    float s = 1.0f / (sqrtf(tot) * (1.0f / 32.0f) + 1e-8f);
    ushort4 o;
    o.x = f2bf(v.x * s); o.y = f2bf(v.y * s);
    o.z = f2bf(v.z * s); o.w = f2bf(v.w * s);
    ((ushort4*)(xn + (size_t)row * D_MODEL))[threadIdx.x] = o;
}

__global__ __launch_bounds__(256) void rowscale_h(const unsigned short* __restrict__ h,
                                                  float* __restrict__ rs) {
    const int row = blockIdx.x;
    const u16x8* hr = (const u16x8*)(h + (size_t)row * D_FF);
    u16x8 a = hr[threadIdx.x * 2 + 0];
    u16x8 b = hr[threadIdx.x * 2 + 1];
    float ss = 0.f;
    #pragma unroll
    for (int j = 0; j < 8; ++j) { float f = bf2f(a[j]); ss += f * f; }
    #pragma unroll
    for (int j = 0; j < 8; ++j) { float f = bf2f(b[j]); ss += f * f; }
    #pragma unroll
    for (int off = 32; off > 0; off >>= 1) ss += __shfl_down(ss, off);
    __shared__ float sm[4];
    int lane = threadIdx.x & 63, wid = threadIdx.x >> 6;
    if (lane == 0) sm[wid] = ss;
    __syncthreads();
    if (threadIdx.x == 0) {
        float tot = sm[0] + sm[1] + sm[2] + sm[3];
        rs[row] = 1.0f / (sqrtf(tot) * (1.0f / 64.0f) + 1e-8f);
    }
}

// ---------------------------------------------------------------------------
// GEMM: C[m][n] = sum_k A[m,k]*B[n,k]   (both K-contiguous)
// LDS: slot s (s = tile&1) at s*65536: A rows 0..255 (quarters @ q*8192),
// B rows 0..255 (@32768 + q*8192). Half-tiles: A{q0,q2}, A{q1,q3},
// B{rows 0-128}, B{rows 128-256} — each 16KB = 2 gloads/thread.
// ---------------------------------------------------------------------------
template <int EPI, int KDIM, int NBLKN>
__global__ __launch_bounds__(512, 2) void gemm8f(const unsigned short* __restrict__ A,
                                                 const unsigned short* __restrict__ B,
                                                 unsigned short* __restrict__ Cbf,
                                                 float* __restrict__ Cf,
                                                 const float* __restrict__ rowscale,
                                                 int nwg) {
    constexpr int NT = KDIM / 64;
    __shared__ char smem[131072];

    const int tid = threadIdx.x;
    const int bid = blockIdx.x;
    const int swz = (bid & 7) * (nwg >> 3) + (bid >> 3);
    const uint m0 = (uint)(swz / NBLKN) * 256u;
    const uint n0 = (uint)(swz % NBLKN) * 256u;

    const int lane = tid & 63;
    const int wid  = tid >> 6;
    const int wm   = wid >> 2;                  // 0..1 -> 128-row slice
    const int wn   = wid & 3;                   // 0..3 -> 64-col slice
    const int lr   = lane & 15;
    const int lk   = lane >> 4;

    // staging: thread covers row (tid>>3) of a 64-row quarter, chunk tid&7,
    // pre-swizzled source (proven 0-conflict layout, R4/R7)
    const uint rowBase = (uint)(tid >> 3);
    const uint colE = (((uint)(tid & 7) << 4) ^ ((rowBase & 7u) << 4)) >> 1;
    const uint aBase = (m0 + rowBase) * (uint)KDIM + colE;
    const uint bBase = (n0 + rowBase) * (uint)KDIM + colE;
    const uint dstOff = (uint)tid * 16u;

    // fragment read offsets
    const uint xorv = ((uint)(lr & 7)) << 4;
    const uint kb0 = (((uint)lk << 4)      ) ^ xorv;
    const uint kb1 = (((uint)lk << 4) | 64u) ^ xorv;
    uint offA[8], offB[4];
    #pragma unroll
    for (int i = 0; i < 8; ++i)
        offA[i] = (uint)(wm * 128 + i * 16 + lr) * 128u;
    #pragma unroll
    for (int i = 0; i < 4; ++i)
        offB[i] = 32768u + (uint)(wn * 64 + i * 16 + lr) * 128u;

    f32x4 acc[8][4];
    #pragma unroll
    for (int mi = 0; mi < 8; ++mi)
        #pragma unroll
        for (int ni = 0; ni < 4; ++ni)
            acc[mi][ni] = (f32x4){0.f, 0.f, 0.f, 0.f};

    // ---- prologue: stage tiles 0 (slot0) and 1 (slot1), 16 gloads ----
    {
        char* s0 = smem;
        char* s1 = smem + 65536;
        gload_lds16(A + aBase +   0u * KDIM, s0 +     0 + dstOff);   // A q0
        gload_lds16(A + aBase + 128u * KDIM, s0 + 16384 + dstOff);   // A q2
        gload_lds16(B + bBase +   0u * KDIM, s0 + 32768 +     0 + dstOff);
        gload_lds16(B + bBase +  64u * KDIM, s0 + 32768 +  8192 + dstOff);
        gload_lds16(A + aBase +  64u * KDIM, s0 +  8192 + dstOff);   // A q1
        gload_lds16(A + aBase + 192u * KDIM, s0 + 24576 + dstOff);   // A q3
        gload_lds16(B + bBase + 128u * KDIM, s0 + 32768 + 16384 + dstOff);
        gload_lds16(B + bBase + 192u * KDIM, s0 + 32768 + 24576 + dstOff);
        gload_lds16(A + aBase +   0u * KDIM + 64u, s1 +     0 + dstOff);
        gload_lds16(A + aBase + 128u * KDIM + 64u, s1 + 16384 + dstOff);
        gload_lds16(B + bBase +   0u * KDIM + 64u, s1 + 32768 +     0 + dstOff);
        gload_lds16(B + bBase +  64u * KDIM + 64u, s1 + 32768 +  8192 + dstOff);
        gload_lds16(A + aBase +  64u * KDIM + 64u, s1 +  8192 + dstOff);
        gload_lds16(A + aBase + 192u * KDIM + 64u, s1 + 24576 + dstOff);
        gload_lds16(B + bBase + 128u * KDIM + 64u, s1 + 32768 + 16384 + dstOff);
        gload_lds16(B + bBase + 192u * KDIM + 64u, s1 + 32768 + 24576 + dstOff);
    }
    VMCNT(8);            // tile 0 landed; tile 1 (8) in flight
    barrier_raw();

#define MFMA16(MB, NB, AV0, AV1, BV0, BV1)                                     \
    __builtin_amdgcn_s_setprio(1);                                             \
    _Pragma("unroll")                                                          \
    for (int mi = 0; mi < 4; ++mi)                                             \
        _Pragma("unroll")                                                      \
        for (int ni = 0; ni < 2; ++ni)                                         \
            acc[(MB) + mi][(NB) + ni] = __builtin_amdgcn_mfma_f32_16x16x32_bf16(\
                AV0[mi], BV0[ni], acc[(MB) + mi][(NB) + ni], 0, 0, 0);         \
    _Pragma("unroll")                                                          \
    for (int mi = 0; mi < 4; ++mi)                                             \
        _Pragma("unroll")                                                      \
        for (int ni = 0; ni < 2; ++ni)                                         \
            acc[(MB) + mi][(NB) + ni] = __builtin_amdgcn_mfma_f32_16x16x32_bf16(\
                AV1[mi], BV1[ni], acc[(MB) + mi][(NB) + ni], 0, 0, 0);         \
    __builtin_amdgcn_s_setprio(0);

    #pragma unroll 1
    for (int it = 0; it < NT / 2; ++it) {
        const int T = it * 2;
        const char* c0 = smem;
        const char* c1 = smem + 65536;
        char* s0 = smem;
        char* s1 = smem + 65536;
        const bool doS = (T + 2 < NT);
        const uint k2 = (uint)(T + 2) * 64u;
        const uint k3 = (uint)(T + 3) * 64u;
        bf16x8 av0[4], av1[4], bc0k0[2], bc0k1[2], bc1k0[2], bc1k1[2];

        // ===== ph1: tile T, Q0 (A-h0 x B-c0); 12 reads =====
        #pragma unroll
        for (int i = 0; i < 4; ++i) {
            av0[i] = *(const bf16x8*)(c0 + offA[i] + kb0);
            av1[i] = *(const bf16x8*)(c0 + offA[i] + kb1);
        }
        #pragma unroll
        for (int i = 0; i < 2; ++i) {
            bc0k0[i] = *(const bf16x8*)(c0 + offB[i] + kb0);
            bc0k1[i] = *(const bf16x8*)(c0 + offB[i] + kb1);
        }
        LGKM8();
        barrier_raw();
        LGKM0();
        MFMA16(0, 0, av0, av1, bc0k0, bc0k1)
        barrier_raw();

        // ===== ph2: Q1 (A-h0 regs x B-c1); 4 reads; stage A{q0,q2}(T+2) =====
        #pragma unroll
        for (int i = 0; i < 2; ++i) {
            bc1k0[i] = *(const bf16x8*)(c0 + offB[2 + i] + kb0);
            bc1k1[i] = *(const bf16x8*)(c0 + offB[2 + i] + kb1);
        }
        if (doS) {
            gload_lds16(A + aBase +   0u * KDIM + k2, s0 +     0 + dstOff);
            gload_lds16(A + aBase + 128u * KDIM + k2, s0 + 16384 + dstOff);
        }
        barrier_raw();
        LGKM0();
        MFMA16(0, 2, av0, av1, bc1k0, bc1k1)
        barrier_raw();

        // ===== ph3: Q3 (A-h1 x B-c1 regs); 8 reads; stage B-h0(T+2) =====
        #pragma unroll
        for (int i = 0; i < 4; ++i) {
            av0[i] = *(const bf16x8*)(c0 + offA[4 + i] + kb0);
            av1[i] = *(const bf16x8*)(c0 + offA[4 + i] + kb1);
        }
        if (doS) {
            gload_lds16(B + bBase +   0u * KDIM + k2, s0 + 32768 +    0 + dstOff);
            gload_lds16(B + bBase +  64u * KDIM + k2, s0 + 32768 + 8192 + dstOff);
        }
        barrier_raw();
        LGKM0();
        MFMA16(4, 2, av0, av1, bc1k0, bc1k1)
        barrier_raw();

        // ===== ph4: Q2 (A-h1 regs x B-c0 regs); stage A{q1,q3}(T+2); vmcnt =====
        if (doS) {
            gload_lds16(A + aBase +  64u * KDIM + k2, s0 +  8192 + dstOff);
            gload_lds16(A + aBase + 192u * KDIM + k2, s0 + 24576 + dstOff);
        }
        barrier_raw();
        MFMA16(4, 0, av0, av1, bc0k0, bc0k1)
        if (doS) { VMCNT(6); } else { VMCNT(0); }   // tile T+1 fully landed
        barrier_raw();

        // ===== ph5: tile T+1, Q0; 12 reads; stage B-h1(T+2) =====
        #pragma unroll
        for (int i = 0; i < 4; ++i) {
            av0[i] = *(const bf16x8*)(c1 + offA[i] + kb0);
            av1[i] = *(const bf16x8*)(c1 + offA[i] + kb1);
        }
        #pragma unroll
        for (int i = 0; i < 2; ++i) {
            bc0k0[i] = *(const bf16x8*)(c1 + offB[i] + kb0);
            bc0k1[i] = *(const bf16x8*)(c1 + offB[i] + kb1);
        }
        if (doS) {
            gload_lds16(B + bBase + 128u * KDIM + k2, s0 + 32768 + 16384 + dstOff);
            gload_lds16(B + bBase + 192u * KDIM + k2, s0 + 32768 + 24576 + dstOff);
        }
        LGKM8();
        barrier_raw();
        LGKM0();
        MFMA16(0, 0, av0, av1, bc0k0, bc0k1)
        barrier_raw();

        // ===== ph6: Q1; 4 reads; stage A{q0,q2}(T+3) =====
        #pragma unroll
        for (int i = 0; i < 2; ++i) {
            bc1k0[i] = *(const bf16x8*)(c1 + offB[2 + i] + kb0);
            bc1k1[i] = *(const bf16x8*)(c1 + offB[2 + i] + kb1);
        }
        if (doS) {
            gload_lds16(A + aBase +   0u * KDIM + k3, s1 +     0 + dstOff);
            gload_lds16(A + aBase + 128u * KDIM + k3, s1 + 16384 + dstOff);
        }
        barrier_raw();
        LGKM0();
        MFMA16(0, 2, av0, av1, bc1k0, bc1k1)
        barrier_raw();

        // ===== ph7: Q3; 8 reads; stage B-h0(T+3) =====
        #pragma unroll
        for (int i = 0; i < 4; ++i) {
            av0[i] = *(const bf16x8*)(c1 + offA[4 + i] + kb0);
            av1[i] = *(const bf16x8*)(c1 + offA[4 + i] + kb1);
        }
        if (doS) {
            gload_lds16(B + bBase +   0u * KDIM + k3, s1 + 32768 +    0 + dstOff);
            gload_lds16(B + bBase +  64u * KDIM + k3, s1 + 32768 + 8192 + dstOff);
        }
        barrier_raw();
        LGKM0();
        MFMA16(4, 2, av0, av1, bc1k0, bc1k1)
        barrier_raw();

        // ===== ph8: Q2; stage A{q1,q3}(T+3) + B-h1(T+3); vmcnt(8) =====
        if (doS) {
            gload_lds16(A + aBase +  64u * KDIM + k3, s1 +  8192 + dstOff);
            gload_lds16(A + aBase + 192u * KDIM + k3, s1 + 24576 + dstOff);
            gload_lds16(B + bBase + 128u * KDIM + k3, s1 + 32768 + 16384 + dstOff);
            gload_lds16(B + bBase + 192u * KDIM + k3, s1 + 32768 + 24576 + dstOff);
        }
        barrier_raw();
        MFMA16(4, 0, av0, av1, bc0k0, bc0k1)
        if (doS) { VMCNT(8); }                      // tile T+2 fully landed
        barrier_raw();
    }
#undef MFMA16

    // epilogue: C/D frag mapping col = lane&15, row = (lane>>4)*4 + reg
    constexpr uint N = (uint)NBLKN * 256u;
    #pragma unroll
    for (int mi = 0; mi < 8; ++mi) {
        #pragma unroll
        for (int j = 0; j < 4; ++j) {
            const uint gr = m0 + (uint)(wm * 128 + mi * 16 + lk * 4 + j);
            float s = 0.f;
            if (EPI == 1) s = rowscale[gr];
            #pragma unroll
            for (int ni = 0; ni < 4; ++ni) {
                const uint gc = n0 + (uint)(wn * 64 + ni * 16 + lr);
                float v = acc[mi][ni][j];
                if (EPI == 0) {
                    Cbf[gr * N + gc] = f2bf(gelu_fast(v));
                } else {
                    Cf[gr * N + gc] = v * s;
                }
            }
        }
    }
}

// ---------------------------------------------------------------------------
extern "C" void kernel_launch(void* const* d_in, const int* in_sizes, int n_in,
                              void* d_out, int out_size, void* d_ws, size_t ws_size,
                              hipStream_t stream) {
    const float* x    = (const float*)d_in[0];
    const float* w_up = (const float*)d_in[1];
    const float* w_dn = (const float*)d_in[2];
    float* out = (float*)d_out;

    uint8_t* ws = (uint8_t*)d_ws;
    unsigned short* h   = (unsigned short*)(ws);                       // 128 MB
    unsigned short* xn  = (unsigned short*)(ws + 134217728);           // 32 MB
    unsigned short* wqu = (unsigned short*)(ws + 134217728 + 33554432);
    unsigned short* wqd = (unsigned short*)(ws + 134217728 + 33554432 + 8388608);
    float*  rs   = (float*)(ws + 134217728 + 33554432 + 2 * 8388608);
    double* alph = (double*)(ws + 134217728 + 33554432 + 2 * 8388608 + 65536);

    hipMemsetAsync(alph, 0, 16, stream);

    absmean_reduce<<<256, 256, 0, stream>>>(w_up, alph + 0);
    absmean_reduce<<<256, 256, 0, stream>>>(w_dn, alph + 1);
    quant_kernel<<<NW / 1024, 256, 0, stream>>>(w_up, alph + 0, wqu);
    quant_kernel<<<NW / 1024, 256, 0, stream>>>(w_dn, alph + 1, wqd);
    rmsnorm_x<<<M_ROWS, 256, 0, stream>>>(x, xn);

    // L1: h = gelu(xn @ wqu^T)  [16384 x 4096], K=1024 -> 64x16 = 1024 blocks
    gemm8f<0, D_MODEL, 16><<<1024, 512, 0, stream>>>(
        xn, wqu, h, nullptr, nullptr, 1024);

    rowscale_h<<<M_ROWS, 256, 0, stream>>>(h, rs);

    // L2: out = (h @ wqd^T) * rs[m]  [16384 x 1024], K=4096 -> 64x4 = 256 blocks
    gemm8f<1, D_FF, 4><<<256, 512, 0, stream>>>(
        h, wqd, nullptr, out, rs, 256);
}